// Round 20
// baseline (127.058 us; speedup 1.0000x reference)
//
#include <hip/hip_runtime.h>

// ---------------------------------------------------------------------------
// MultiHeadAttentionWindow: B=8 K=4000 D=256 H=8 DQ=DV=32 WIN=200 PAD=50 STEP=100
// Pipeline (8 launches): prep_weights; cvt_qkv (fp32->bf16 stream, ceiling);
//   gemmR<0,0>(q) (k) (v) [bf16 HOT A + row-major writes = out_gemm's proven
//   6us regime]; vtrans; attn_win (clamp-K); gemmR<0,1>(out).
// Round-20: COMBINE the two fixes that were only ever tested separately:
//   - r15 proved bf16-A alone insufficient (kept vt scatter -> 60us)
//   - r16 proved scatter-fix alone insufficient (kept cold fp32-A -> 80us)
//   - out_gemm (both fixes) = ~6us every round since r13.
//   cvt_qkv streams the fp32 inputs ONCE at ~6TB/s (r15-measured), then all
//   four GEMMs run in the bf16-hot-A row-major regime.
// ---------------------------------------------------------------------------

typedef __bf16 bf16_t;
typedef __bf16 bf16x8 __attribute__((ext_vector_type(8)));
typedef float  f32x4  __attribute__((ext_vector_type(4)));

#define MFMA16(a, b, c) __builtin_amdgcn_mfma_f32_16x16x32_bf16((a), (b), (c), 0, 0, 0)

typedef __attribute__((address_space(1))) const unsigned char gas_u8;
typedef __attribute__((address_space(3))) unsigned char las_u8;

static __device__ __forceinline__ void gload16(const void* g, void* l) {
  __builtin_amdgcn_global_load_lds((gas_u8*)g, (las_u8*)l, 16, 0, 0);
}

static __device__ __forceinline__ bf16x8 cvt8(float4 a, float4 b) {
  bf16x8 r;
  r[0] = (bf16_t)a.x; r[1] = (bf16_t)a.y; r[2] = (bf16_t)a.z; r[3] = (bf16_t)a.w;
  r[4] = (bf16_t)b.x; r[5] = (bf16_t)b.y; r[6] = (bf16_t)b.z; r[7] = (bf16_t)b.w;
  return r;
}

static __device__ __forceinline__ unsigned short bbits(bf16_t v) {
  union { bf16_t b; unsigned short u; } c; c.b = v; return c.u;
}

// ---- weight transpose + bf16 convert: Wt[n][k] = bf16(W[k][n]), 4 matrices ----
__global__ __launch_bounds__(256)
void prep_weights(const float* __restrict__ Wq, const float* __restrict__ Wk,
                  const float* __restrict__ Wv, const float* __restrict__ Wo,
                  bf16_t* __restrict__ wt) {
  const int mat  = blockIdx.x >> 6;
  const int tile = blockIdx.x & 63;
  const int kt = (tile >> 3) * 32, nt = (tile & 7) * 32;
  const float* W = (mat == 0) ? Wq : (mat == 1) ? Wk : (mat == 2) ? Wv : Wo;
  __shared__ float t[32][33];
  const int tx = threadIdx.x & 31, ty = threadIdx.x >> 5;  // ty 0..7
#pragma unroll
  for (int i = 0; i < 32; i += 8)
    t[ty + i][tx] = W[(size_t)(kt + ty + i) * 256 + nt + tx];
  __syncthreads();
  bf16_t* dst = wt + (size_t)mat * 65536;
#pragma unroll
  for (int i = 0; i < 32; i += 8)
    dst[(size_t)(nt + ty + i) * 256 + kt + tx] = (bf16_t)t[tx][ty + i];
}

// ---- pure streaming convert: q/k/v fp32 -> xb[3][M][256] bf16 (~ceiling) ----
__global__ __launch_bounds__(256)
void cvt_qkv(const float* __restrict__ qx, const float* __restrict__ kx,
             const float* __restrict__ vx, bf16_t* __restrict__ xb, int M) {
  const float* X = (blockIdx.y == 0) ? qx : (blockIdx.y == 1) ? kx : vx;
  bf16_t* O = xb + (size_t)blockIdx.y * M * 256;
  const int total = M * 32;            // 8-elem groups
  const int stride = gridDim.x * 256;
  for (int i = blockIdx.x * 256 + threadIdx.x; i < total; i += stride) {
    const float4 a = ((const float4*)X)[(size_t)i * 2];
    const float4 b = ((const float4*)X)[(size_t)i * 2 + 1];
    *(bf16x8*)&O[(size_t)i * 8] = cvt8(a, b);
  }
}

// ---- GEMM: [M x 256] (bf16) x [256 x 256] + bias -> ROW-MAJOR out.
// 64m x 256n, 4 waves, per-K-tile double-buffered gload, counted vmcnt.
// OUTF32: output fp32 else bf16 (*oscale).
template <int OUTF32>
__global__ __launch_bounds__(256)
void gemmR(const bf16_t* __restrict__ Xv, const bf16_t* __restrict__ W,
           const float* __restrict__ bias, void* __restrict__ Out, int M,
           float oscale) {
  constexpr int ASZ = 4096;
  constexpr int STRIDE = ASZ + 16384;
  __shared__ __align__(16) char lds[2 * STRIDE];

  const int tid  = threadIdx.x;
  const int lane = tid & 63;
  const int w    = tid >> 6;           // wave 0..3
  const int lo   = lane & 15, hi = lane >> 4;
  const int m0   = blockIdx.x * 64;

  // A staging: 256 slots x 16B; slot s: row=s>>2, cs=s&3 holds chunk cs^(row&3)
  const bf16_t* asrc;
  int aoff;
  {
    const int s = tid;
    const int row = s >> 2, cs = s & 3;
    int ar = m0 + row; if (ar >= M) ar = M - 1;
    asrc = Xv + (size_t)ar * 256 + ((cs ^ (row & 3)) << 3);
    aoff = s * 16;
  }
  // B staging: 4 gloads; slot s: row=s>>2, ch=s&3 (linear)
  const bf16_t* bsrc[4];
  int boff[4];
#pragma unroll
  for (int j = 0; j < 4; ++j) {
    const int s = j * 256 + tid;
    bsrc[j] = W + (size_t)(s >> 2) * 256 + ((s & 3) << 3);
    boff[j] = ASZ + s * 16;
  }
  int bbase[4];
#pragma unroll
  for (int ni = 0; ni < 4; ++ni)
    bbase[ni] = ASZ + (w * 64 + ni * 16 + lo) * 64 + hi * 16;

  // prologue: issue tile 0 into buffer 0
  gload16(asrc, lds + aoff);
#pragma unroll
  for (int j = 0; j < 4; ++j) gload16(bsrc[j], lds + boff[j]);

  f32x4 acc[4][4] = {};

  for (int t = 0; t < 8; ++t) {
    const int cur = (t & 1) * STRIDE;
    if (t < 7) {
      const int nxt = ((t + 1) & 1) * STRIDE;
      gload16(asrc + (t + 1) * 32, lds + nxt + aoff);
#pragma unroll
      for (int j = 0; j < 4; ++j)
        gload16(bsrc[j] + (t + 1) * 32, lds + nxt + boff[j]);
      asm volatile("s_waitcnt vmcnt(5)" ::: "memory");   // tile t landed
    } else {
      asm volatile("s_waitcnt vmcnt(0)" ::: "memory");
    }
    __builtin_amdgcn_sched_barrier(0);
    __builtin_amdgcn_s_barrier();

    bf16x8 af[4], bfv[4];
#pragma unroll
    for (int mi = 0; mi < 4; ++mi) {
      const int r = mi * 16 + lo;
      const int ab = cur + r * 64 + ((hi ^ (r & 3)) << 4);
      af[mi] = *(const bf16x8*)(lds + ab);
    }
#pragma unroll
    for (int ni = 0; ni < 4; ++ni)
      bfv[ni] = *(const bf16x8*)(lds + cur + bbase[ni]);
#pragma unroll
    for (int mi = 0; mi < 4; ++mi)
#pragma unroll
      for (int ni = 0; ni < 4; ++ni)
        acc[mi][ni] = MFMA16(af[mi], bfv[ni], acc[mi][ni]);
    __builtin_amdgcn_sched_barrier(0);
    __builtin_amdgcn_s_barrier();
  }

  // epilogue: C/D layout col = lane&15, row = (lane>>4)*4 + r  [m89-verified]
#pragma unroll
  for (int mi = 0; mi < 4; ++mi) {
    const int mb = m0 + mi * 16 + hi * 4;   // 4-aligned; M % 4 == 0
    if (mb >= M) continue;
#pragma unroll
    for (int ni = 0; ni < 4; ++ni) {
      const int n = w * 64 + ni * 16 + lo;
      const float bia = bias[n];
      if constexpr (OUTF32) {
        float* O = (float*)Out;
#pragma unroll
        for (int rr = 0; rr < 4; ++rr)
          O[(size_t)(mb + rr) * 256 + n] = acc[mi][ni][rr] + bia;
      } else {
        bf16_t* O = (bf16_t*)Out;
#pragma unroll
        for (int rr = 0; rr < 4; ++rr)
          O[(size_t)(mb + rr) * 256 + n] = (bf16_t)((acc[mi][ni][rr] + bia) * oscale);
      }
    }
  }
}

// ---- vb [b][4000][256] -> vt [b*256+n][4064] (p = t+50), + left-pad ----
// grid (63, 4, bc); 64t x 64n tile per block; both sides coalesced.
// Store guarded at t<4000.
__global__ __launch_bounds__(256)
void vtrans(const bf16_t* __restrict__ vb, bf16_t* __restrict__ vt) {
  const int t0 = blockIdx.x * 64, n0 = blockIdx.y * 64, b = blockIdx.z;
  __shared__ bf16_t T[64][72];         // T[n][t]
  const int tid = threadIdx.x;
#pragma unroll
  for (int u = 0; u < 2; ++u) {
    const int s = u * 256 + tid;       // 512 slots: row=s>>3, cc=s&7
    const int row = s >> 3, cc = s & 7;
    int t = t0 + row; if (t > 3999) t = 3999;
    const bf16x8 v = *(const bf16x8*)&vb[((size_t)b * 4000 + t) * 256 + n0 + cc * 8];
#pragma unroll
    for (int e = 0; e < 8; ++e) T[cc * 8 + e][row] = v[e];
  }
  __syncthreads();
#pragma unroll
  for (int u = 0; u < 2; ++u) {
    const int s = u * 256 + tid;
    const int nr = s >> 3, cc = s & 7;
    const int tb = t0 + cc * 8;        // first t covered by this chunk
    bf16_t* dst = vt + ((size_t)b * 256 + n0 + nr) * 4064 + 50 + tb;
    const bf16_t* src = &T[nr][cc * 8];
#pragma unroll
    for (int e = 0; e < 4; ++e)        // each unsigned covers t = tb+2e, tb+2e+1
      if (tb + 2 * e < 4000)
        ((unsigned*)dst)[e] = ((const unsigned*)src)[e];
  }
  if (blockIdx.x == 0 && tid < 64) {   // replicate left pad p<50 := V[0][n]
    const unsigned short e = bbits(T[tid][0]);
    const unsigned vv = (unsigned)e | ((unsigned)e << 16);
    unsigned* P = (unsigned*)(vt + ((size_t)b * 256 + n0 + tid) * 4064);
#pragma unroll
    for (int p = 0; p < 25; ++p) P[p] = vv;
  }
}

// ---- windowed attention: one block per (b',h,window), 7 waves = 7 row-strips ----
// K read ROW-MAJOR with clamp(t) = replicate pad (left edge = K[0]; right-tail
// entries are provably causally masked, E == exact 0). vt rows (b*256+n).
__global__ __launch_bounds__(448)
void attn_win(const bf16_t* __restrict__ qb, const bf16_t* __restrict__ kr,
              const bf16_t* __restrict__ vt, bf16_t* __restrict__ ao) {
  const int blk = blockIdx.x;
  const int n = blk % 40;
  const int h = (blk / 40) & 7;
  const int b = blk / 320;
  const int wv = threadIdx.x >> 6;     // strip 0..6, rows i in [50+16wv, 66+16wv)
  const int lane = threadIdx.x & 63;
  const int lo = lane & 15, hi = lane >> 4;

  __shared__ __align__(16) bf16_t E[7][16][40];  // per-wave 16x32 chunk (pad 40)

  const int i0 = 50 + 16 * wv;
  int jtmax = (65 + 16 * wv) >> 4;     // last 16-tile with any unmasked element
  if (jtmax > 9) jtmax = 9;
  const int reach = jtmax * 16 + 16;

  // Q fragment (pre-scaled by 1/sqrt(200)): row lo -> token t = n*100+16wv+lo
  int tq = n * 100 + 16 * wv + lo;
  if (tq > 3999) tq = 3999;            // rows i>=150 are discarded at store
  const bf16x8 qf = *(const bf16x8*)&qb[((size_t)b * 4000 + tq) * 256 + h * 32 + hi * 8];

  const f32x4 zero = {0.f, 0.f, 0.f, 0.f};
  bf16x8 onesf;
#pragma unroll
  for (int u = 0; u < 8; ++u) onesf[u] = (bf16_t)1.0f;

  f32x4 o0 = zero, o1 = zero, sm = zero;
  const size_t vbase = ((size_t)(b * 256 + h * 32)) * 4064 + n * 100;
  const int dbase = i0 + hi * 4 - lo;  // d = dbase + r - 16*jt

#pragma unroll
  for (int kt = 0; kt < 5; ++kt) if (kt * 32 < reach) {
    // two score tiles -> E chunk [16][32]
#pragma unroll
    for (int half = 0; half < 2; ++half) {
      const int jt = kt * 2 + half;
      if (jt <= jtmax) {
        int tk = n * 100 + jt * 16 + lo - 50;          // clamp = edge pad
        tk = (tk < 0) ? 0 : (tk > 3999 ? 3999 : tk);
        const bf16x8 kf = *(const bf16x8*)&kr[((size_t)b * 4000 + tk) * 256 + h * 32 + hi * 8];
        const f32x4 s = MFMA16(qf, kf, zero);
#pragma unroll
        for (int r = 0; r < 4; ++r) {
          const int d = dbase + r - jt * 16;
          const float df = (float)d;
          float c = __builtin_amdgcn_rcpf(__builtin_fmaf(0.25f * df, df, 1.f));
          c = (d == 0) ? 0.f : c;      // eye-mask: diagonal score -> 0 -> e=1
          float e = __expf(s[r] * c);
          e = (d < 0) ? 0.f : e;       // causal mask
          E[wv][hi * 4 + r][half * 16 + lo] = (bf16_t)e;
        }
      } else {
#pragma unroll
        for (int r = 0; r < 4; ++r)
          E[wv][hi * 4 + r][half * 16 + lo] = (bf16_t)0.f;
      }
    }
    // PV + denom for this 32-col chunk (wave-private LDS, in-order DS)
    const bf16x8 pf = *(const bf16x8*)&E[wv][lo][hi * 8];
    const bf16x8 v0 = *(const bf16x8*)&vt[vbase + (size_t)lo * 4064 + kt * 32 + hi * 8];
    const bf16x8 v1 = *(const bf16x8*)&vt[vbase + (size_t)(16 + lo) * 4064 + kt * 32 + hi * 8];
    o0 = MFMA16(pf, v0, o0);
    o1 = MFMA16(pf, v1, o1);
    sm = MFMA16(pf, onesf, sm);
  }

  // store central rows (i in [50,150)): out = o * rcp(rowsum); rowsum >= 1
#pragma unroll
  for (int r = 0; r < 4; ++r) {
    const int i = i0 + hi * 4 + r;
    if (i < 150) {
      const float ri = __builtin_amdgcn_rcpf(sm[r]);
      const int t = n * 100 + i - 50;
      bf16_t* op = &ao[((size_t)b * 4000 + t) * 256 + h * 32];
      op[lo]      = (bf16_t)(o0[r] * ri);
      op[16 + lo] = (bf16_t)(o1[r] * ri);
    }
  }
}

// ---------------------------------------------------------------------------
extern "C" void kernel_launch(void* const* d_in, const int* in_sizes, int n_in,
                              void* d_out, int out_size, void* d_ws, size_t ws_size,
                              hipStream_t stream) {
  (void)in_sizes; (void)n_in; (void)out_size;
  const float* query = (const float*)d_in[0];
  const float* key   = (const float*)d_in[1];
  const float* value = (const float*)d_in[2];
  const float* Wq = (const float*)d_in[3];
  const float* bq = (const float*)d_in[4];
  const float* Wk = (const float*)d_in[5];
  const float* bk = (const float*)d_in[6];
  const float* Wv = (const float*)d_in[7];
  const float* bv = (const float*)d_in[8];
  const float* Wo = (const float*)d_in[9];
  const float* bo = (const float*)d_in[10];

  // per-batch bytes: xb 6.144M + qb 2.048M + kr 2.048M + vb 2.048M +
  // vt 2.081M + ao 2.048M = 16.417M; + wt 0.524M
  int bc = 8;
  while (bc > 1 && 524288ull + (unsigned long long)bc * 16417536ull > (unsigned long long)ws_size)
    bc >>= 1;

  bf16_t* wt = (bf16_t*)d_ws;                           // 4 * 65536
  bf16_t* xb = wt + 4 * 65536;                          // 3*bc*4000*256
  bf16_t* qb = xb + (size_t)3 * bc * 4000 * 256;        // bc*4000*256
  bf16_t* kr = qb + (size_t)bc * 4000 * 256;            // bc*4000*256
  bf16_t* vb = kr + (size_t)bc * 4000 * 256;            // bc*4000*256
  bf16_t* vt = vb + (size_t)bc * 4000 * 256;            // bc*256*4064
  bf16_t* ao = vt + (size_t)bc * 256 * 4064;            // bc*4000*256

  prep_weights<<<256, 256, 0, stream>>>(Wq, Wk, Wv, Wo, wt);

  const float qscale = 0.07071067811865475f;  // 1/sqrt(200) folded into qb

  for (int b0 = 0; b0 < 8; b0 += bc) {
    const int M = bc * 4000;
    const int mblk = (M + 63) / 64;
    const float* qx = query + (size_t)b0 * 4000 * 256;
    const float* kx = key   + (size_t)b0 * 4000 * 256;
    const float* vx = value + (size_t)b0 * 4000 * 256;
    float* ox = (float*)d_out + (size_t)b0 * 4000 * 256;

    cvt_qkv<<<dim3(1024, 3), 256, 0, stream>>>(qx, kx, vx, xb, M);
    gemmR<0><<<mblk, 256, 0, stream>>>(xb + 0 * (size_t)M * 256, wt + 0 * 65536, bq, qb, M, qscale);
    gemmR<0><<<mblk, 256, 0, stream>>>(xb + 1 * (size_t)M * 256, wt + 1 * 65536, bk, kr, M, 1.f);
    gemmR<0><<<mblk, 256, 0, stream>>>(xb + 2 * (size_t)M * 256, wt + 2 * 65536, bv, vb, M, 1.f);
    vtrans<<<dim3(63, 4, bc), 256, 0, stream>>>(vb, vt);
    attn_win<<<bc * 320, 448, 0, stream>>>(qb, kr, vt, ao);
    gemmR<1><<<mblk, 256, 0, stream>>>(ao, wt + 3 * 65536, bo, ox, M, 1.f);
  }
}